// Round 2
// baseline (1221.644 us; speedup 1.0000x reference)
//
#include <hip/hip_runtime.h>
#include <cstdint>
#include <cstddef>

// B=2, S=2048, HID=1024, NH=16, HD=64. logn scale == 1.0 (provable no-op).
#define NB_ 2
#define SS 2048
#define HIDN 1024
#define NHH 16
#define HDD 64

typedef __attribute__((ext_vector_type(8))) short bf16x8;
typedef __attribute__((ext_vector_type(4))) float f32x4;
typedef __attribute__((ext_vector_type(4))) unsigned short u16x4;
typedef __attribute__((ext_vector_type(8))) unsigned short u16x8;

static __device__ __forceinline__ unsigned short f2bf(float f) {
  union { float f; uint32_t u; } c{f};
  uint32_t u = c.u;
  u += 0x7FFFu + ((u >> 16) & 1u);
  return (unsigned short)(u >> 16);
}

// ---------------------------------------------------------------------------
// C = A(M,K)f32 @ W(N,K)^T f32 + bias, inputs converted to bf16 during LDS
// staging, MFMA 16x16x32_bf16, fp32 accum. 128x128 tile, BK=64, 256 thr.
// MODE 0: scatter C -> (B,NH,S,HD) bf16      (Q, K projections; N==1024)
// MODE 2: scatter C -> (B,NH,HD,S) bf16      (V projection, transposed)
// MODE 1: C row-major (M,N) f32              (final output)
// Fragment maps (gfx950, 16x16x32): A lane l = A[l&15][8*(l>>4)+j];
// B lane l = B[8*(l>>4)+j][l&15]; D lane l reg r = D[4*(l>>4)+r][l&15].
// (k-order within a window is self-consistent between A and B, so only the
//  lane&15 row/col map — verified via m89's C/D layout — must be right.)
// ---------------------------------------------------------------------------
template <int MODE>
__global__ __launch_bounds__(256) void gemm_bf16(
    const float* __restrict__ A, const float* __restrict__ W,
    const float* __restrict__ bias, void* __restrict__ Cptr,
    int N, int K)
{
  __shared__ unsigned short As[128][72];   // +8 pad: stride 36 dw = free 2-way
  __shared__ unsigned short Ws[128][72];

  const int tid = threadIdx.x;
  const int lane = tid & 63, w = tid >> 6;
  const int wm = w >> 1, wn = w & 1;
  const int l15 = lane & 15, g = lane >> 4;
  const int m0 = blockIdx.y << 7, n0 = blockIdx.x << 7;

  f32x4 acc[4][4] = {};   // [mb][nb]

  for (int k0 = 0; k0 < K; k0 += 64) {
    __syncthreads();
#pragma unroll
    for (int i = 0; i < 8; ++i) {
      const int f = (i << 8) + tid;          // 0..2047 over 128x16 float4s
      const int row = f >> 4, c4 = (f & 15) << 2;
      const float4 va = *(const float4*)(A + (size_t)(m0 + row) * K + k0 + c4);
      const float4 vw = *(const float4*)(W + (size_t)(n0 + row) * K + k0 + c4);
      u16x4 ha, hw;
      ha.x = f2bf(va.x); ha.y = f2bf(va.y); ha.z = f2bf(va.z); ha.w = f2bf(va.w);
      hw.x = f2bf(vw.x); hw.y = f2bf(vw.y); hw.z = f2bf(vw.z); hw.w = f2bf(vw.w);
      *(u16x4*)&As[row][c4] = ha;
      *(u16x4*)&Ws[row][c4] = hw;
    }
    __syncthreads();
#pragma unroll
    for (int kw = 0; kw < 2; ++kw) {
      bf16x8 af[4], bfr[4];
#pragma unroll
      for (int mb = 0; mb < 4; ++mb)
        af[mb] = *(const bf16x8*)&As[(wm << 6) + (mb << 4) + l15][(kw << 5) + (g << 3)];
#pragma unroll
      for (int nb = 0; nb < 4; ++nb)
        bfr[nb] = *(const bf16x8*)&Ws[(wn << 6) + (nb << 4) + l15][(kw << 5) + (g << 3)];
#pragma unroll
      for (int mb = 0; mb < 4; ++mb)
#pragma unroll
        for (int nb = 0; nb < 4; ++nb)
          acc[mb][nb] = __builtin_amdgcn_mfma_f32_16x16x32_bf16(
              af[mb], bfr[nb], acc[mb][nb], 0, 0, 0);
    }
  }

  float bv[4];
#pragma unroll
  for (int nb = 0; nb < 4; ++nb)
    bv[nb] = bias[n0 + (wn << 6) + (nb << 4) + l15];

#pragma unroll
  for (int mb = 0; mb < 4; ++mb) {
#pragma unroll
    for (int nb = 0; nb < 4; ++nb) {
      const int n = n0 + (wn << 6) + (nb << 4) + l15;
#pragma unroll
      for (int r = 0; r < 4; ++r) {
        const int m = m0 + (wm << 6) + (mb << 4) + (g << 2) + r;
        const float v = acc[mb][nb][r] + bv[nb];
        if (MODE == 1) {
          ((float*)Cptr)[(size_t)m * N + n] = v;
        } else {
          const int bb = m >> 11, s = m & (SS - 1);
          const int hh = n >> 6, d = n & (HDD - 1);
          unsigned short* C16 = (unsigned short*)Cptr;
          if (MODE == 0)
            C16[((((size_t)bb * NHH + hh) * SS + s) << 6) + d] = f2bf(v);
          else   // MODE 2: V transposed (B,NH,HD,S)
            C16[(((size_t)bb * NHH + hh) * HDD + d) * SS + s] = f2bf(v);
        }
      }
    }
  }
}

// ---------------------------------------------------------------------------
// Causal flash attention, MFMA bf16, fp32 online softmax.
// Block: 256 thr = 4 waves; q-tile 64 rows (wave w owns rows w*16..w*16+15),
// kv-tile 64. Q/K bf16 (B,NH,S,HD); V bf16 transposed (B,NH,HD,S).
// Epilogue: /l, * exp(agg_w), write f32 concat buffer (B,S,2*HID).
// ---------------------------------------------------------------------------
__global__ __launch_bounds__(256) void attn_mfma(
    const unsigned short* __restrict__ Qw, const unsigned short* __restrict__ Kw,
    const unsigned short* __restrict__ Vw, const float* __restrict__ agg_w,
    float* __restrict__ att, int branch)
{
  __shared__ unsigned short Ks[64][72];      // [j][d]
  __shared__ unsigned short Vs[64][72];      // [d][j]  (from transposed V)
  __shared__ unsigned short Ps[4][16][72];   // per-wave P [q][j]

  const int tid = threadIdx.x, lane = tid & 63, w = tid >> 6;
  const int l15 = lane & 15, g = lane >> 4;
  const int qt = blockIdx.x, h = blockIdx.y, b = blockIdx.z;
  const int q0 = qt << 6;
  const size_t headoff = ((size_t)b * NHH + h) * (size_t)SS * HDD;
  const unsigned short* Qh = Qw + headoff;
  const unsigned short* Kh = Kw + headoff;
  const unsigned short* Vh = Vw + headoff;   // [d][s]

  bf16x8 qf[2];
  qf[0] = *(const bf16x8*)(Qh + (size_t)(q0 + (w << 4) + l15) * HDD + (g << 3));
  qf[1] = *(const bf16x8*)(Qh + (size_t)(q0 + (w << 4) + l15) * HDD + 32 + (g << 3));

  f32x4 oacc[4] = {};
  float m_run[4], l_run[4];
#pragma unroll
  for (int r = 0; r < 4; ++r) { m_run[r] = -1e30f; l_run[r] = 0.f; }

  for (int t = 0; t <= qt; ++t) {
    const int j0 = t << 6;
    __syncthreads();
#pragma unroll
    for (int i = 0; i < 2; ++i) {
      const int f = (i << 8) + tid;          // 0..511 over 64x8 chunks
      const int row = f >> 3, c8 = (f & 7) << 3;
      *(u16x8*)&Ks[row][c8] = *(const u16x8*)(Kh + (size_t)(j0 + row) * HDD + c8);
      *(u16x8*)&Vs[row][c8] = *(const u16x8*)(Vh + (size_t)row * SS + j0 + c8);
    }
    __syncthreads();

    // QK^T: S[16q][64j] per wave
    f32x4 sacc[4] = {};
#pragma unroll
    for (int kw = 0; kw < 2; ++kw) {
#pragma unroll
      for (int nb = 0; nb < 4; ++nb) {
        const bf16x8 kf = *(const bf16x8*)&Ks[(nb << 4) + l15][(kw << 5) + (g << 3)];
        sacc[nb] = __builtin_amdgcn_mfma_f32_16x16x32_bf16(qf[kw], kf, sacc[nb], 0, 0, 0);
      }
    }

    // scale + causal mask (diag tile only)
    const bool diag = (t == qt);
    const int qgb = q0 + (w << 4) + (g << 2);
#pragma unroll
    for (int nb = 0; nb < 4; ++nb) {
      const int jg = j0 + (nb << 4) + l15;
#pragma unroll
      for (int r = 0; r < 4; ++r) {
        float s = sacc[nb][r] * 0.125f;       // 1/sqrt(64)
        if (diag && jg > qgb + r) s = -1e30f;
        sacc[nb][r] = s;
      }
    }

    // online softmax, one running (m,l) per q-row r
#pragma unroll
    for (int r = 0; r < 4; ++r) {
      float mloc = fmaxf(fmaxf(sacc[0][r], sacc[1][r]),
                         fmaxf(sacc[2][r], sacc[3][r]));
      mloc = fmaxf(mloc, __shfl_xor(mloc, 1, 16));
      mloc = fmaxf(mloc, __shfl_xor(mloc, 2, 16));
      mloc = fmaxf(mloc, __shfl_xor(mloc, 4, 16));
      mloc = fmaxf(mloc, __shfl_xor(mloc, 8, 16));
      const float mnew = fmaxf(m_run[r], mloc);
      const float corr = __expf(m_run[r] - mnew);
      m_run[r] = mnew;
      float psum = 0.f;
#pragma unroll
      for (int nb = 0; nb < 4; ++nb) {
        const float p = __expf(sacc[nb][r] - mnew);
        sacc[nb][r] = p; psum += p;
      }
      psum += __shfl_xor(psum, 1, 16);
      psum += __shfl_xor(psum, 2, 16);
      psum += __shfl_xor(psum, 4, 16);
      psum += __shfl_xor(psum, 8, 16);
      l_run[r] = l_run[r] * corr + psum;
#pragma unroll
      for (int nb = 0; nb < 4; ++nb) oacc[nb][r] *= corr;
    }

    // P -> per-wave LDS (bf16), then PV (same-wave dep, no barrier needed)
#pragma unroll
    for (int nb = 0; nb < 4; ++nb)
#pragma unroll
      for (int r = 0; r < 4; ++r)
        Ps[w][(g << 2) + r][(nb << 4) + l15] = f2bf(sacc[nb][r]);

#pragma unroll
    for (int kw = 0; kw < 2; ++kw) {
      const bf16x8 pf = *(const bf16x8*)&Ps[w][l15][(kw << 5) + (g << 3)];
#pragma unroll
      for (int nb = 0; nb < 4; ++nb) {
        const bf16x8 vf = *(const bf16x8*)&Vs[(nb << 4) + l15][(kw << 5) + (g << 3)];
        oacc[nb] = __builtin_amdgcn_mfma_f32_16x16x32_bf16(pf, vf, oacc[nb], 0, 0, 0);
      }
    }
  }

  // epilogue
  const int colb = branch * HIDN + (h << 6);
#pragma unroll
  for (int nb = 0; nb < 4; ++nb) {
    const int d = (nb << 4) + l15;
    const float aw = __expf(agg_w[colb + d]);
#pragma unroll
    for (int r = 0; r < 4; ++r) {
      const int q = q0 + (w << 4) + (g << 2) + r;
      att[(size_t)(b * SS + q) * (2 * HIDN) + colb + d] =
          oacc[nb][r] / l_run[r] * aw;
    }
  }
}

// ---------------------------------------------------------------------------
extern "C" void kernel_launch(void* const* d_in, const int* in_sizes, int n_in,
                              void* d_out, int out_size, void* d_ws, size_t ws_size,
                              hipStream_t stream) {
  (void)in_sizes; (void)n_in; (void)out_size; (void)ws_size;

  const float* x_in[2] = { (const float*)d_in[0], (const float*)d_in[1] };
  const float* agg_w = (const float*)d_in[14];
  const float* W_out = (const float*)d_in[15];
  const float* b_out = (const float*)d_in[16];

  const size_t QKV_ELEMS = (size_t)NB_ * NHH * SS * HDD;   // 4,194,304
  unsigned short* q_ws = (unsigned short*)d_ws;
  unsigned short* k_ws = q_ws + QKV_ELEMS;
  unsigned short* v_ws = k_ws + QKV_ELEMS;                  // transposed layout
  float* att_ws = (float*)(v_ws + QKV_ELEMS);               // (B,S,2*HID) f32

  const dim3 blk(256);
  const dim3 gproj(HIDN / 128, (NB_ * SS) / 128);           // 8 x 32
  const dim3 gattn(SS / 64, NHH, NB_);                      // 32 x 16 x 2
  const dim3 gout(HIDN / 128, (NB_ * SS) / 128);            // 8 x 32

  for (int br = 0; br < 2; ++br) {
    const int base = 2 + br * 6;
    const float* Wq = (const float*)d_in[base + 0];
    const float* bq = (const float*)d_in[base + 1];
    const float* Wk = (const float*)d_in[base + 2];
    const float* bk = (const float*)d_in[base + 3];
    const float* Wv = (const float*)d_in[base + 4];
    const float* bv = (const float*)d_in[base + 5];

    gemm_bf16<0><<<gproj, blk, 0, stream>>>(x_in[br], Wq, bq, q_ws, HIDN, HIDN);
    gemm_bf16<0><<<gproj, blk, 0, stream>>>(x_in[br], Wk, bk, k_ws, HIDN, HIDN);
    gemm_bf16<2><<<gproj, blk, 0, stream>>>(x_in[br], Wv, bv, v_ws, HIDN, HIDN);
    attn_mfma<<<gattn, blk, 0, stream>>>(q_ws, k_ws, v_ws, agg_w, att_ws, br);
  }

  gemm_bf16<1><<<gout, blk, 0, stream>>>(att_ws, W_out, b_out, (float*)d_out,
                                         HIDN, 2 * HIDN);
}

// Round 9
// 466.822 us; speedup vs baseline: 2.6169x; 2.6169x over previous
//
#include <hip/hip_runtime.h>
#include <cstdint>
#include <cstddef>

// B=2, S=2048, HID=1024, NH=16, HD=64. logn scale == 1.0 (provable no-op).
#define NB_ 2
#define SS 2048
#define HIDN 1024
#define NHH 16
#define HDD 64

typedef unsigned short u16;
typedef __attribute__((ext_vector_type(8))) short bf16x8;
typedef __attribute__((ext_vector_type(4))) float f32x4;
typedef __attribute__((ext_vector_type(4))) u16 u16x4;
typedef __attribute__((ext_vector_type(8))) u16 u16x8;

static __device__ __forceinline__ u16 f2bf(float f) {
  union { float f; uint32_t u; } c{f};
  uint32_t u = c.u;
  u += 0x7FFFu + ((u >> 16) & 1u);
  return (u16)(u >> 16);
}

// async global->LDS, 16B per lane; lds ptr must be wave-uniform, global per-lane
static __device__ __forceinline__ void gl_lds16(const void* g, void* l) {
  __builtin_amdgcn_global_load_lds(
      (const __attribute__((address_space(1))) void*)g,
      (__attribute__((address_space(3))) void*)l, 16, 0, 0);
}

// ---------------------------------------------------------------------------
// one-shot f32 -> bf16 conversion of x (both modalities) + 7 weight matrices
// dst is ONE contiguous bf16 region; segment s src pointers differ.
// ---------------------------------------------------------------------------
struct CvtArgs { const float* src[9]; unsigned start[10]; };  // starts in float4 units

__global__ __launch_bounds__(256) void cvt_bf16(CvtArgs a, u16* __restrict__ dst) {
  const unsigned total = a.start[9];
  for (unsigned id = blockIdx.x * 256 + threadIdx.x; id < total;
       id += gridDim.x * 256) {
    int seg = 0;
    while (id >= a.start[seg + 1]) ++seg;
    const float4 v = ((const float4*)a.src[seg])[id - a.start[seg]];
    u16x4 h;
    h.x = f2bf(v.x); h.y = f2bf(v.y); h.z = f2bf(v.z); h.w = f2bf(v.w);
    *(u16x4*)(dst + (size_t)id * 4) = h;
  }
}

// ---------------------------------------------------------------------------
// Fused QKV projection, both branches. C = x(4096,1024) @ W(1024,1024)^T + b.
// grid (24, 32, 2): x = n-tile (0-7 Q, 8-15 K, 16-23 V), y = m-tile, z = branch.
// bf16 in (pre-converted), global_load_lds staging, 128x128 tile, BK=64,
// mfma_f32_16x16x32_bf16, f32 accum. Epilogue repacks through XOR-swizzled
// LDS so ALL global stores are coalesced u16x8:
//   Q,K -> (B,NH,S,HD) bf16 ;  V -> (B,NH,HD,S) bf16 (transposed).
// ---------------------------------------------------------------------------
struct Ptrs6 { const float* p[6]; };

__global__ __launch_bounds__(256) void gemm_qkv(
    const u16* __restrict__ xb, const u16* __restrict__ wb, Ptrs6 bias,
    u16* __restrict__ qb, u16* __restrict__ kb, u16* __restrict__ vb)
{
  __shared__ union { u16 ab[2][128][64]; u16 t[128][128]; } sm;
  const int tid = threadIdx.x, lane = tid & 63, w = tid >> 6;
  const int wm = w >> 1, wn = w & 1, l15 = lane & 15, g = lane >> 4;
  const int nt = blockIdx.x, m0 = blockIdx.y << 7, z = blockIdx.z;
  const int which = nt >> 3;            // 0=Q 1=K 2=V
  const int nloc = (nt & 7) << 7;       // n offset within this weight
  const u16* Ab = xb + (size_t)z * 4194304u;
  const u16* Wb = wb + (size_t)(z * 3 + which) * 1048576u;
  const int rl = lane >> 3, cl = (lane & 7) << 3;

  f32x4 acc[4][4] = {};

  for (int k0 = 0; k0 < 1024; k0 += 64) {
    __syncthreads();                       // prev compute done: LDS reusable
#pragma unroll
    for (int i = 0; i < 4; ++i) {
      const int row = (i << 5) + (w << 3);
      gl_lds16(Ab + (size_t)(m0 + row + rl) * 1024 + k0 + cl, &sm.ab[0][row][0]);
      gl_lds16(Wb + (size_t)(nloc + row + rl) * 1024 + k0 + cl, &sm.ab[1][row][0]);
    }
    __syncthreads();                       // drains vmcnt: tiles resident
#pragma unroll
    for (int kw = 0; kw < 2; ++kw) {
      bf16x8 af[4], bf[4];
#pragma unroll
      for (int mb = 0; mb < 4; ++mb)
        af[mb] = *(const bf16x8*)&sm.ab[0][(wm << 6) + (mb << 4) + l15][(kw << 5) + (g << 3)];
#pragma unroll
      for (int nb = 0; nb < 4; ++nb)
        bf[nb] = *(const bf16x8*)&sm.ab[1][(wn << 6) + (nb << 4) + l15][(kw << 5) + (g << 3)];
#pragma unroll
      for (int mb = 0; mb < 4; ++mb)
#pragma unroll
        for (int nb = 0; nb < 4; ++nb)
          acc[mb][nb] = __builtin_amdgcn_mfma_f32_16x16x32_bf16(
              af[mb], bf[nb], acc[mb][nb], 0, 0, 0);
    }
  }

  float bv[4];
  const float* bp = bias.p[z * 3 + which];
#pragma unroll
  for (int nb = 0; nb < 4; ++nb)
    bv[nb] = bp[nloc + (wn << 6) + (nb << 4) + l15];

  __syncthreads();   // everyone done reading sm.ab
  if (which < 2) {   // repack as t[m][n ^ swz(m)]
#pragma unroll
    for (int mb = 0; mb < 4; ++mb)
#pragma unroll
      for (int nb = 0; nb < 4; ++nb) {
        const int n = (wn << 6) + (nb << 4) + l15;
#pragma unroll
        for (int r = 0; r < 4; ++r) {
          const int m = (wm << 6) + (mb << 4) + (g << 2) + r;
          sm.t[m][n ^ ((m & 7) << 4)] = f2bf(acc[mb][nb][r] + bv[nb]);
        }
      }
  } else {           // V: repack transposed t[n][m ^ swz(n)]
#pragma unroll
    for (int nb = 0; nb < 4; ++nb)
#pragma unroll
      for (int mb = 0; mb < 4; ++mb) {
        const int n = (wn << 6) + (nb << 4) + l15;
        const int mb4 = (wm << 6) + (mb << 4) + (g << 2);
        u16x4 h;
        h.x = f2bf(acc[mb][nb][0] + bv[nb]);
        h.y = f2bf(acc[mb][nb][1] + bv[nb]);
        h.z = f2bf(acc[mb][nb][2] + bv[nb]);
        h.w = f2bf(acc[mb][nb][3] + bv[nb]);
        *(u16x4*)&sm.t[n][mb4 ^ ((n & 7) << 4)] = h;
      }
  }
  __syncthreads();

  u16* dst = (which == 0) ? qb : (which == 1) ? kb : vb;
  dst += (size_t)z * 4194304u;
  const int bb = m0 >> 11, m0loc = m0 & (SS - 1), hh0 = nloc >> 6;
#pragma unroll
  for (int it = 0; it < 8; ++it) {
    const int id = (it << 8) + tid;
    const int a_ = id >> 4, cb8 = (id & 15) << 3;
    const u16x8 v = *(const u16x8*)&sm.t[a_][cb8 ^ ((a_ & 7) << 4)];
    size_t off;
    if (which < 2) {   // a_ = m-local (s), cb8 = n-local (head,d)
      const int hh = hh0 + (cb8 >> 6), d = cb8 & 63, s = m0loc + a_;
      off = ((((size_t)bb * NHH + hh) * SS + s) << 6) + d;
    } else {           // a_ = n-local (head,d), cb8 = m-local (s)
      const int hh = hh0 + (a_ >> 6), d = a_ & 63, s = m0loc + cb8;
      off = ((((size_t)bb * NHH + hh) * HDD + d) << 11) + s;
    }
    *(u16x8*)(dst + off) = v;
  }
}

// ---------------------------------------------------------------------------
// Causal flash attention, MFMA bf16, fp32 online softmax; BOTH branches in one
// dispatch: grid (32, 16, 4), z = branch*2 + b. Q/K (B,NH,S,HD); V transposed.
// Output: bf16 concat buffer (B,S,2*HID) with exp(agg_w) fused.
// ---------------------------------------------------------------------------
__global__ __launch_bounds__(256) void attn_mfma(
    const u16* __restrict__ Qw, const u16* __restrict__ Kw,
    const u16* __restrict__ Vw, const float* __restrict__ agg_w,
    u16* __restrict__ att)
{
  __shared__ u16 Ks[64][72];      // [j][d]
  __shared__ u16 Vs[64][72];      // [d][j]  (from transposed V)
  __shared__ u16 Ps[4][16][72];   // per-wave P [q][j]

  const int tid = threadIdx.x, lane = tid & 63, w = tid >> 6;
  const int l15 = lane & 15, g = lane >> 4;
  const int qt = blockIdx.x, h = blockIdx.y;
  const int b = blockIdx.z & 1, br = blockIdx.z >> 1;
  const int q0 = qt << 6;
  const size_t broff = (size_t)br * 4194304u;
  const size_t headoff = ((size_t)b * NHH + h) * (size_t)SS * HDD;
  const u16* Qh = Qw + broff + headoff;
  const u16* Kh = Kw + broff + headoff;
  const u16* Vh = Vw + broff + headoff;   // [d][s]

  bf16x8 qf[2];
  qf[0] = *(const bf16x8*)(Qh + (size_t)(q0 + (w << 4) + l15) * HDD + (g << 3));
  qf[1] = *(const bf16x8*)(Qh + (size_t)(q0 + (w << 4) + l15) * HDD + 32 + (g << 3));

  f32x4 oacc[4] = {};
  float m_run[4], l_run[4];
#pragma unroll
  for (int r = 0; r < 4; ++r) { m_run[r] = -1e30f; l_run[r] = 0.f; }

  for (int t = 0; t <= qt; ++t) {
    const int j0 = t << 6;
    __syncthreads();
#pragma unroll
    for (int i = 0; i < 2; ++i) {
      const int f = (i << 8) + tid;
      const int row = f >> 3, c8 = (f & 7) << 3;
      *(u16x8*)&Ks[row][c8] = *(const u16x8*)(Kh + (size_t)(j0 + row) * HDD + c8);
      *(u16x8*)&Vs[row][c8] = *(const u16x8*)(Vh + (size_t)row * SS + j0 + c8);
    }
    __syncthreads();

    f32x4 sacc[4] = {};
#pragma unroll
    for (int kw = 0; kw < 2; ++kw) {
#pragma unroll
      for (int nb = 0; nb < 4; ++nb) {
        const bf16x8 kf = *(const bf16x8*)&Ks[(nb << 4) + l15][(kw << 5) + (g << 3)];
        sacc[nb] = __builtin_amdgcn_mfma_f32_16x16x32_bf16(qf[kw], kf, sacc[nb], 0, 0, 0);
      }
    }

    const bool diag = (t == qt);
    const int qgb = q0 + (w << 4) + (g << 2);
#pragma unroll
    for (int nb = 0; nb < 4; ++nb) {
      const int jg = j0 + (nb << 4) + l15;
#pragma unroll
      for (int r = 0; r < 4; ++r) {
        float s = sacc[nb][r] * 0.125f;
        if (diag && jg > qgb + r) s = -1e30f;
        sacc[nb][r] = s;
      }
    }

#pragma unroll
    for (int r = 0; r < 4; ++r) {
      float mloc = fmaxf(fmaxf(sacc[0][r], sacc[1][r]),
                         fmaxf(sacc[2][r], sacc[3][r]));
      mloc = fmaxf(mloc, __shfl_xor(mloc, 1, 16));
      mloc = fmaxf(mloc, __shfl_xor(mloc, 2, 16));
      mloc = fmaxf(mloc, __shfl_xor(mloc, 4, 16));
      mloc = fmaxf(mloc, __shfl_xor(mloc, 8, 16));
      const float mnew = fmaxf(m_run[r], mloc);
      const float corr = __expf(m_run[r] - mnew);
      m_run[r] = mnew;
      float psum = 0.f;
#pragma unroll
      for (int nb = 0; nb < 4; ++nb) {
        const float p = __expf(sacc[nb][r] - mnew);
        sacc[nb][r] = p; psum += p;
      }
      psum += __shfl_xor(psum, 1, 16);
      psum += __shfl_xor(psum, 2, 16);
      psum += __shfl_xor(psum, 4, 16);
      psum += __shfl_xor(psum, 8, 16);
      l_run[r] = l_run[r] * corr + psum;
#pragma unroll
      for (int nb = 0; nb < 4; ++nb) oacc[nb][r] *= corr;
    }

#pragma unroll
    for (int nb = 0; nb < 4; ++nb)
#pragma unroll
      for (int r = 0; r < 4; ++r)
        Ps[w][(g << 2) + r][(nb << 4) + l15] = f2bf(sacc[nb][r]);

#pragma unroll
    for (int kw = 0; kw < 2; ++kw) {
      const bf16x8 pf = *(const bf16x8*)&Ps[w][l15][(kw << 5) + (g << 3)];
#pragma unroll
      for (int nb = 0; nb < 4; ++nb) {
        const bf16x8 vf = *(const bf16x8*)&Vs[(nb << 4) + l15][(kw << 5) + (g << 3)];
        oacc[nb] = __builtin_amdgcn_mfma_f32_16x16x32_bf16(pf, vf, oacc[nb], 0, 0, 0);
      }
    }
  }

  const int colb = br * HIDN + (h << 6);
#pragma unroll
  for (int nb = 0; nb < 4; ++nb) {
    const int d = (nb << 4) + l15;
    const float aw = __expf(agg_w[colb + d]);
#pragma unroll
    for (int r = 0; r < 4; ++r) {
      const int q = q0 + (w << 4) + (g << 2) + r;
      att[(size_t)(b * SS + q) * (2 * HIDN) + colb + d] =
          f2bf(oacc[nb][r] / l_run[r] * aw);
    }
  }
}

// ---------------------------------------------------------------------------
// Final GEMM: out = att(4096,2048)bf16 @ W_out(1024,2048)^T bf16 + b_out, f32 out.
// BM=64, BN=128, BK=64 -> grid (8, 64) = 512 blocks.
// ---------------------------------------------------------------------------
__global__ __launch_bounds__(256) void gemm_out(
    const u16* __restrict__ Ab, const u16* __restrict__ Wb,
    const float* __restrict__ bias, float* __restrict__ out)
{
  __shared__ u16 As[64][64];
  __shared__ u16 Ws[128][64];
  const int tid = threadIdx.x, lane = tid & 63, w = tid >> 6;
  const int wm = w >> 1, wn = w & 1, l15 = lane & 15, g = lane >> 4;
  const int n0 = blockIdx.x << 7, m0 = blockIdx.y << 6;
  const int rl = lane >> 3, cl = (lane & 7) << 3;

  f32x4 acc[2][4] = {};

  for (int k0 = 0; k0 < 2048; k0 += 64) {
    __syncthreads();
#pragma unroll
    for (int i = 0; i < 2; ++i) {
      const int row = (i << 5) + (w << 3);
      gl_lds16(Ab + (size_t)(m0 + row + rl) * 2048 + k0 + cl, &As[row][0]);
    }
#pragma unroll
    for (int i = 0; i < 4; ++i) {
      const int row = (i << 5) + (w << 3);
      gl_lds16(Wb + (size_t)(n0 + row + rl) * 2048 + k0 + cl, &Ws[row][0]);
    }
    __syncthreads();
#pragma unroll
    for (int kw = 0; kw < 2; ++kw) {
      bf16x8 af[2], bf[4];
#pragma unroll
      for (int mb = 0; mb < 2; ++mb)
        af[mb] = *(const bf16x8*)&As[(wm << 5) + (mb << 4) + l15][(kw << 5) + (g << 3)];
#pragma unroll
      for (int nb = 0; nb < 4; ++nb)
        bf[nb] = *(const bf16x8*)&Ws[(wn << 6) + (nb << 4) + l15][(kw << 5) + (g << 3)];
#pragma unroll
      for (int mb = 0; mb < 2; ++mb)
#pragma unroll
        for (int nb = 0; nb < 4; ++nb)
          acc[mb][nb] = __builtin_amdgcn_mfma_f32_16x16x32_bf16(
              af[mb], bf[nb], acc[mb][nb], 0, 0, 0);
    }
  }

#pragma unroll
  for (int mb = 0; mb < 2; ++mb)
#pragma unroll
    for (int nb = 0; nb < 4; ++nb) {
      const int n = n0 + (wn << 6) + (nb << 4) + l15;
      const float bvn = bias[n];
#pragma unroll
      for (int r = 0; r < 4; ++r) {
        const int m = m0 + (wm << 5) + (mb << 4) + (g << 2) + r;
        out[(size_t)m * HIDN + n] = acc[mb][nb][r] + bvn;
      }
    }
}

// ---------------------------------------------------------------------------
extern "C" void kernel_launch(void* const* d_in, const int* in_sizes, int n_in,
                              void* d_out, int out_size, void* d_ws, size_t ws_size,
                              hipStream_t stream) {
  (void)in_sizes; (void)n_in; (void)out_size; (void)ws_size;

  const float* agg_w = (const float*)d_in[14];
  const float* b_out = (const float*)d_in[16];

  // ws layout (u16 offsets):
  u16* ws    = (u16*)d_ws;
  u16* xb    = ws;                    //  8,388,608 : eeg_b, ecg_b
  u16* wb    = ws + 8388608u;         //  6,291,456 : Wq/Wk/Wv eeg, Wq/Wk/Wv ecg
  u16* wob   = ws + 14680064u;        //  2,097,152 : W_out bf16
  u16* q_ws  = ws + 16777216u;        //  8,388,608 : Q both branches (B,NH,S,HD)
  u16* k_ws  = ws + 25165824u;        //  8,388,608 : K
  u16* v_ws  = ws + 33554432u;        //  8,388,608 : V transposed (B,NH,HD,S)
  u16* att_b = ws + 41943040u;        //  8,388,608 : concat att (B,S,2*HID) bf16

  CvtArgs ca;
  ca.src[0] = (const float*)d_in[0];   // eeg
  ca.src[1] = (const float*)d_in[1];   // ecg
  ca.src[2] = (const float*)d_in[2];   // Wq_eeg
  ca.src[3] = (const float*)d_in[4];   // Wk_eeg
  ca.src[4] = (const float*)d_in[6];   // Wv_eeg
  ca.src[5] = (const float*)d_in[8];   // Wq_ecg
  ca.src[6] = (const float*)d_in[10];  // Wk_ecg
  ca.src[7] = (const float*)d_in[12];  // Wv_ecg
  ca.src[8] = (const float*)d_in[15];  // W_out
  const unsigned st[10] = {0u, 1048576u, 2097152u, 2359296u, 2621440u,
                           2883584u, 3145728u, 3407872u, 3670016u, 4194304u};
  for (int i = 0; i < 10; ++i) ca.start[i] = st[i];

  Ptrs6 bp;
  bp.p[0] = (const float*)d_in[3];   // bq_eeg
  bp.p[1] = (const float*)d_in[5];   // bk_eeg
  bp.p[2] = (const float*)d_in[7];   // bv_eeg
  bp.p[3] = (const float*)d_in[9];   // bq_ecg
  bp.p[4] = (const float*)d_in[11];  // bk_ecg
  bp.p[5] = (const float*)d_in[13];  // bv_ecg

  cvt_bf16<<<2048, 256, 0, stream>>>(ca, ws);
  gemm_qkv<<<dim3(24, 32, 2), 256, 0, stream>>>(xb, wb, bp, q_ws, k_ws, v_ws);
  attn_mfma<<<dim3(32, 16, 4), 256, 0, stream>>>(q_ws, k_ws, v_ws, agg_w, att_b);
  gemm_out<<<dim3(8, 64), 256, 0, stream>>>(att_b, wob, b_out, (float*)d_out);
}